// Round 7
// baseline (2235.296 us; speedup 1.0000x reference)
//
#include <hip/hip_runtime.h>
#include <hip/hip_bf16.h>

#define ALPHA 0.2f
#define NB 256
// N=1024 particles, F_IN=6, NH=64, H=4 heads, T=12 steps.
// Identity 1: attend values are LINEAR in the 6-dim input row -> head attends run
//   in 6-dim space; ELU(hv@W)@Wout is a per-row pointwise afterwards.
// Identity 2: leaky-relu scores are threshold-separable:
//   w_ij = eb_i*exp(d_j)       if d_j >= -s_i
//        = ea_i*exp(a*d_j)     else
//   -> bin d_j by value (monotone binning => only the boundary bin needs exact
//   per-element checks), per-bin sums + bin prefix => O(1) per row.

// ---------------- dtype detect + convert (unchanged) ----------------
__global__ void k_detect(const unsigned short* __restrict__ s, int n, int* __restrict__ flag){
  int i = blockIdx.x * 256 + threadIdx.x;
  if (i < n){
    unsigned short u = s[i];
    if ((u & 0x7F80u) == 0x7F80u) atomicOr(flag, 1);
  }
}

struct Ptr13 { const void* p[13]; };
__global__ void k_cvtAll(Ptr13 src, float* __restrict__ xs, float* __restrict__ wsW,
                         const int* __restrict__ flag){
  const int n = blockIdx.x * 256 + threadIdx.x;
  const int F = *flag;
  if (n < 73728){
    xs[n] = F ? ((const float*)src.p[0])[n]
              : __bfloat162float(((const __hip_bfloat16*)src.p[0])[n]);
    return;
  }
  const int m = n - 73728;
  if (m >= 10788) return;
  const int segend[12] = {1536,2048,3584,3596,5132,5644,7180,7192,8728,9240,10776,10788};
  const int dstoff[12] = {0,1536,2048,3584,3600,5136,5648,7184,7200,8736,9248,10784};
  int seg = 0;
  #pragma unroll
  for (int i = 0; i < 12; ++i) if (m >= segend[i]) seg = i + 1;
  const int local = m - (seg ? segend[seg - 1] : 0);
  float v;
  if (F) v = ((const float*)src.p[seg + 1])[local];
  else   v = __bfloat162float(((const __hip_bfloat16*)src.p[seg + 1])[local]);
  wsW[dstoff[seg] + local] = v;
}

// Wa[L][h][sd][8] = W @ a halves; also zero the inter-block barrier counter.
__global__ void k_prew(const float* __restrict__ wsW, float* __restrict__ WaG,
                       int* __restrict__ bar)
{
  if (threadIdx.x == 200) *bar = 0;
  if (threadIdx.x < 144){
    const int d = threadIdx.x;
    const int L = d / 48, r2 = d % 48, h = r2 / 12, sd = (r2 % 12) / 6, f = r2 % 6;
    const int Woff[3] = {0, 3600, 7200};     // Wx, Wh, Wy
    const int aoff[3] = {1536, 5136, 8736};  // ax, ah, ay
    float s = 0.f;
    for (int k = 0; k < 64; ++k)
      s += wsW[Woff[L] + h * 384 + f * 64 + k] * wsW[aoff[L] + h * 128 + sd * 64 + k];
    WaG[((L * 4 + h) * 2 + sd) * 8 + f] = s;
  }
}

// ---------------- core: O(1)-per-row attend via value-binning ----------------
// thread i owns row i (1024 threads). v7 = features + trailing 1.0 (for den).
// s = row source score, d = row dest score. Output hv[6] = attended/normalized.
__device__ __forceinline__ void attend6(
    const float v7[7], float s, float d,
    float* __restrict__ sdL, float* __restrict__ sQ, float* __restrict__ sP,
    float* __restrict__ binQ, float* __restrict__ binP,
    int* __restrict__ hist, int* __restrict__ off, int* __restrict__ cur,
    int* __restrict__ wtotI, float* __restrict__ wtotF, float* __restrict__ red,
    float hv[6])
{
  const int t = threadIdx.x, wid = t >> 6, lane = t & 63;
  // block min/max of d
  float mx = d, mn = d;
  #pragma unroll
  for (int m = 1; m < 64; m <<= 1){
    mx = fmaxf(mx, __shfl_xor(mx, m, 64));
    mn = fminf(mn, __shfl_xor(mn, m, 64));
  }
  if (lane == 0){ red[wid] = mx; red[16 + wid] = mn; }
  __syncthreads();
  if (t == 0){
    float a = red[0], b = red[16];
    for (int w = 1; w < 16; ++w){ a = fmaxf(a, red[w]); b = fminf(b, red[16 + w]); }
    red[0] = a; red[1] = b;
  }
  __syncthreads();
  const float dmax = red[0], dmin = red[1];

  if (dmax - dmin < 1e-12f){
    // all d (numerically) equal -> uniform softmax -> mean. Exact for h=0 start.
    float a7[7];
    #pragma unroll
    for (int c = 0; c < 7; ++c){
      float v = v7[c];
      #pragma unroll
      for (int m = 1; m < 64; m <<= 1) v += __shfl_xor(v, m, 64);
      a7[c] = v;
    }
    if (lane == 0){
      #pragma unroll
      for (int c = 0; c < 7; ++c) sQ[wid * 7 + c] = a7[c];
    }
    __syncthreads();
    if (t == 0){
      float tot[7] = {0,0,0,0,0,0,0};
      for (int w = 0; w < 16; ++w)
        #pragma unroll
        for (int c = 0; c < 7; ++c) tot[c] += sQ[w * 7 + c];
      #pragma unroll
      for (int c = 0; c < 7; ++c) red[c] = tot[c];
    }
    __syncthreads();
    const float invn = 1.f / red[6];
    #pragma unroll
    for (int c = 0; c < 6; ++c) hv[c] = red[c] * invn;
    __syncthreads();
    return;
  }

  const float scale = (float)NB / (dmax - dmin);
  if (t < NB) hist[t] = 0;
  __syncthreads();
  int b = (int)((d - dmin) * scale);
  b = b < 0 ? 0 : (b > NB - 1 ? NB - 1 : b);
  atomicAdd(&hist[b], 1);
  __syncthreads();
  // exclusive scan of hist -> off[0..NB]; cur = off copy
  int incl = 0;
  if (t < NB){
    incl = hist[t];
    #pragma unroll
    for (int m = 1; m < 64; m <<= 1){
      int u = __shfl_up(incl, m, 64);
      if (lane >= m) incl += u;
    }
    if (lane == 63) wtotI[wid] = incl;
  }
  __syncthreads();
  if (t < NB){
    int add = 0;
    for (int w = 0; w < wid; ++w) add += wtotI[w];
    const int inclp = incl + add;
    off[t + 1] = inclp;
    if (t == 0) off[0] = 0;
    cur[t] = inclp - hist[t];           // == off[t]
  }
  __syncthreads();
  // scatter (d, exp(d)*v, exp(a d)*v) into bin-contiguous order
  const int pos = atomicAdd(&cur[b], 1);
  const float eP = __expf(d), eQ = __expf(ALPHA * d);
  sdL[pos] = d;
  #pragma unroll
  for (int c = 0; c < 7; ++c){ sQ[pos * 7 + c] = eQ * v7[c]; sP[pos * 7 + c] = eP * v7[c]; }
  __syncthreads();
  // per-bin sums + exclusive bin scan (threads < NB, whole waves 0..3)
  float bq[7] = {0,0,0,0,0,0,0}, bp[7] = {0,0,0,0,0,0,0};
  float iq[7], ip[7];
  if (t < NB){
    const int p0 = off[t], p1 = off[t + 1];
    for (int p = p0; p < p1; ++p){
      #pragma unroll
      for (int c = 0; c < 7; ++c){ bq[c] += sQ[p * 7 + c]; bp[c] += sP[p * 7 + c]; }
    }
    #pragma unroll
    for (int c = 0; c < 7; ++c){ iq[c] = bq[c]; ip[c] = bp[c]; }
    #pragma unroll
    for (int m = 1; m < 64; m <<= 1){
      #pragma unroll
      for (int c = 0; c < 7; ++c){
        float uq = __shfl_up(iq[c], m, 64);
        float up = __shfl_up(ip[c], m, 64);
        if (lane >= m){ iq[c] += uq; ip[c] += up; }
      }
    }
    if (lane == 63){
      #pragma unroll
      for (int c = 0; c < 7; ++c){ wtotF[wid * 14 + c] = iq[c]; wtotF[wid * 14 + 7 + c] = ip[c]; }
    }
  }
  __syncthreads();
  if (t < NB){
    float aq[7] = {0,0,0,0,0,0,0}, ap[7] = {0,0,0,0,0,0,0};
    for (int w = 0; w < wid; ++w)
      #pragma unroll
      for (int c = 0; c < 7; ++c){ aq[c] += wtotF[w * 14 + c]; ap[c] += wtotF[w * 14 + 7 + c]; }
    #pragma unroll
    for (int c = 0; c < 7; ++c){
      binQ[t * 7 + c] = iq[c] + aq[c] - bq[c];   // exclusive prefix
      binP[t * 7 + c] = ip[c] + ap[c] - bp[c];
    }
    if (t == NB - 1){
      #pragma unroll
      for (int c = 0; c < 7; ++c) binP[NB * 7 + c] = ip[c] + ap[c];   // total P
    }
  }
  __syncthreads();
  // per-row O(1) + boundary bin
  float mm = s + dmax; mm = fmaxf(mm, ALPHA * mm);
  const float ea = __expf(ALPHA * s - mm), eb = __expf(s - mm);
  const float thr = -s;
  int rb = (int)((thr - dmin) * scale);
  rb = rb < 0 ? 0 : (rb > NB - 1 ? NB - 1 : rb);
  float SQ[7], SP[7];
  #pragma unroll
  for (int c = 0; c < 7; ++c){
    SQ[c] = binQ[rb * 7 + c];                       // bins < rb : d < thr
    SP[c] = binP[NB * 7 + c] - binP[(rb + 1) * 7 + c];  // bins > rb : d >= thr
  }
  const int p0 = off[rb], p1 = off[rb + 1];
  for (int p = p0; p < p1; ++p){
    if (sdL[p] < thr){
      #pragma unroll
      for (int c = 0; c < 7; ++c) SQ[c] += sQ[p * 7 + c];
    } else {
      #pragma unroll
      for (int c = 0; c < 7; ++c) SP[c] += sP[p * 7 + c];
    }
  }
  const float den = ea * SQ[6] + eb * SP[6];
  const float inv = 1.f / den;
  #pragma unroll
  for (int c = 0; c < 6; ++c) hv[c] = (ea * SQ[c] + eb * SP[c]) * inv;
  __syncthreads();
}

// per-row pointwise: y6 = ELU(hv @ W_h) @ Wout_h  (all LDS reads are wave-uniform
// broadcasts -> conflict-free; float2 for pk math)
__device__ __forceinline__ void pointwise6(const float hv[6],
    const float* __restrict__ WS, const float* __restrict__ WoT, float y6[6])
{
  float2 acc[6];
  #pragma unroll
  for (int f = 0; f < 6; ++f) acc[f] = make_float2(0.f, 0.f);
  for (int k = 0; k < 64; k += 2){
    float2 o = make_float2(0.f, 0.f);
    #pragma unroll
    for (int f = 0; f < 6; ++f){
      float2 w = *(const float2*)&WS[f * 64 + k];
      o.x += hv[f] * w.x; o.y += hv[f] * w.y;
    }
    o.x = o.x > 0.f ? o.x : (__expf(o.x) - 1.f);
    o.y = o.y > 0.f ? o.y : (__expf(o.y) - 1.f);
    #pragma unroll
    for (int f = 0; f < 6; ++f){
      float2 w = *(const float2*)&WoT[f * 64 + k];
      acc[f].x += o.x * w.x; acc[f].y += o.y * w.y;
    }
  }
  #pragma unroll
  for (int f = 0; f < 6; ++f) y6[f] = acc[f].x + acc[f].y;
}

#define ATT_SHARED \
  __shared__ float sd_[1024]; \
  __shared__ float sQ_[1024 * 7]; \
  __shared__ float sP_[1024 * 7]; \
  __shared__ float binQ_[(NB + 1) * 7]; \
  __shared__ float binP_[(NB + 1) * 7]; \
  __shared__ int   hist_[NB]; \
  __shared__ int   off_[NB + 1]; \
  __shared__ int   cur_[NB]; \
  __shared__ int   wtotI_[16]; \
  __shared__ float wtotF_[64]; \
  __shared__ float red_[32];

// Stage A: per (head, t): 6-dim head attend + pointwise -> y6 partial.
__launch_bounds__(1024)
__global__ void k_stageA(const float* __restrict__ X, const float* __restrict__ WaL,
                         const float* __restrict__ W64, const float* __restrict__ Wout,
                         float* __restrict__ y6part)
{
  ATT_SHARED
  __shared__ float WS_[384];
  __shared__ float WoT_[384];
  const int h = blockIdx.x, tb = blockIdx.y;
  const int t = threadIdx.x;
  if (t < 384){
    WS_[t] = W64[h * 384 + t];
    const int f = t >> 6, k = t & 63;
    WoT_[f * 64 + k] = Wout[(h * 64 + k) * 6 + f];
  }
  float v7[7];
  {
    const float* xr = X + ((size_t)tb * 1024 + t) * 6;
    #pragma unroll
    for (int c = 0; c < 6; ++c) v7[c] = xr[c];
    v7[6] = 1.f;
  }
  float s = 0.f, d = 0.f;
  #pragma unroll
  for (int c = 0; c < 6; ++c){ s += v7[c] * WaL[h * 16 + c]; d += v7[c] * WaL[h * 16 + 8 + c]; }
  __syncthreads();
  float hv[6];
  attend6(v7, s, d, sd_, sQ_, sP_, binQ_, binP_, hist_, off_, cur_, wtotI_, wtotF_, red_, hv);
  float y6[6];
  pointwise6(hv, WS_, WoT_, y6);
  float* dst = y6part + (((size_t)tb * 4 + h) * 1024 + t) * 6;
  #pragma unroll
  for (int c = 0; c < 6; ++c) dst[c] = y6[c];
}

// Stage B: per t: sum 4 head partials, output attend (K=6).
// MODE 0: f32out[t] = hv (Lx).  MODE 2: outv = addsrc + hv (final, dtype by flag).
template<int MODE>
__launch_bounds__(1024)
__global__ void k_stageB(const float* __restrict__ y6part, const float* __restrict__ ao,
                         const float* __restrict__ addsrc, float* __restrict__ f32out,
                         void* __restrict__ outv, const int* __restrict__ flag)
{
  ATT_SHARED
  const int tb = blockIdx.x;
  const int t = threadIdx.x;
  float v7[7];
  {
    const float* p0 = y6part + (((size_t)tb * 4 + 0) * 1024 + t) * 6;
    const float* p1 = y6part + (((size_t)tb * 4 + 1) * 1024 + t) * 6;
    const float* p2 = y6part + (((size_t)tb * 4 + 2) * 1024 + t) * 6;
    const float* p3 = y6part + (((size_t)tb * 4 + 3) * 1024 + t) * 6;
    #pragma unroll
    for (int c = 0; c < 6; ++c) v7[c] = p0[c] + p1[c] + p2[c] + p3[c];
    v7[6] = 1.f;
  }
  float s = 0.f, d = 0.f;
  #pragma unroll
  for (int c = 0; c < 6; ++c){ s += v7[c] * ao[c]; d += v7[c] * ao[6 + c]; }
  float hv[6];
  attend6(v7, s, d, sd_, sQ_, sP_, binQ_, binP_, hist_, off_, cur_, wtotI_, wtotF_, red_, hv);
  if (MODE == 0){
    float* dst = f32out + ((size_t)tb * 1024 + t) * 6;
    #pragma unroll
    for (int c = 0; c < 6; ++c) dst[c] = hv[c];
  } else {
    const float* a = addsrc + ((size_t)tb * 1024 + t) * 6;
    const int base = (tb * 1024 + t) * 6;
    if (*flag){
      float* dst = (float*)outv;
      #pragma unroll
      for (int c = 0; c < 6; ++c) dst[base + c] = a[c] + hv[c];
    } else {
      __hip_bfloat16* dst = (__hip_bfloat16*)outv;
      #pragma unroll
      for (int c = 0; c < 6; ++c) dst[base + c] = __float2bfloat16(a[c] + hv[c]);
    }
  }
}

// Phase 2: persistent, grid 4 (block = head), all 12 steps inside.
// h lives in registers (thread i owns row i). One inter-block barrier per step;
// y6 partials parity-double-buffered.
__launch_bounds__(1024)
__global__ void k_phase2(const float* __restrict__ Lx, float* __restrict__ h_all,
                         const float* __restrict__ WaL, const float* __restrict__ W64,
                         const float* __restrict__ Wout, const float* __restrict__ ao,
                         float* __restrict__ y6p2, int* __restrict__ bar)
{
  ATT_SHARED
  __shared__ float WS_[384];
  __shared__ float WoT_[384];
  const int hB = blockIdx.x;
  const int t = threadIdx.x;
  if (t < 384){
    WS_[t] = W64[hB * 384 + t];
    const int f = t >> 6, k = t & 63;
    WoT_[f * 64 + k] = Wout[(hB * 64 + k) * 6 + f];
  }
  float was[6], wad[6], aov[12];
  #pragma unroll
  for (int c = 0; c < 6; ++c){ was[c] = WaL[hB * 16 + c]; wad[c] = WaL[hB * 16 + 8 + c]; }
  #pragma unroll
  for (int c = 0; c < 12; ++c) aov[c] = ao[c];
  float h7[7];
  #pragma unroll
  for (int c = 0; c < 6; ++c) h7[c] = 0.f;
  h7[6] = 1.f;
  __syncthreads();

  int par = 0;
  for (int step = 0; step < 12; ++step){
    // ---- A: head attend + pointwise for head hB ----
    float s = 0.f, d = 0.f;
    #pragma unroll
    for (int c = 0; c < 6; ++c){ s += h7[c] * was[c]; d += h7[c] * wad[c]; }
    float hv[6];
    attend6(h7, s, d, sd_, sQ_, sP_, binQ_, binP_, hist_, off_, cur_, wtotI_, wtotF_, red_, hv);
    float y6[6];
    pointwise6(hv, WS_, WoT_, y6);
    {
      float* dst = y6p2 + (((size_t)par * 4 + hB) * 1024 + t) * 6;
      #pragma unroll
      for (int c = 0; c < 6; ++c) dst[c] = y6[c];
    }
    // ---- inter-block barrier (4 blocks, generation-counting) ----
    __threadfence();
    __syncthreads();
    if (t == 0){
      __threadfence();
      atomicAdd(bar, 1);
      const int target = 4 * (step + 1);
      while (atomicAdd(bar, 0) < target) __builtin_amdgcn_s_sleep(1);
      __threadfence();
    }
    __syncthreads();
    // ---- B: output attend over summed y6 (redundant in all blocks) ----
    float v7[7];
    {
      const float* p0 = y6p2 + (((size_t)par * 4 + 0) * 1024 + t) * 6;
      const float* p1 = y6p2 + (((size_t)par * 4 + 1) * 1024 + t) * 6;
      const float* p2 = y6p2 + (((size_t)par * 4 + 2) * 1024 + t) * 6;
      const float* p3 = y6p2 + (((size_t)par * 4 + 3) * 1024 + t) * 6;
      #pragma unroll
      for (int c = 0; c < 6; ++c) v7[c] = p0[c] + p1[c] + p2[c] + p3[c];
      v7[6] = 1.f;
    }
    float s2 = 0.f, d2 = 0.f;
    #pragma unroll
    for (int c = 0; c < 6; ++c){ s2 += v7[c] * aov[c]; d2 += v7[c] * aov[6 + c]; }
    float hvb[6];
    attend6(v7, s2, d2, sd_, sQ_, sP_, binQ_, binP_, hist_, off_, cur_, wtotI_, wtotF_, red_, hvb);
    {
      const float* lx = Lx + ((size_t)step * 1024 + t) * 6;
      #pragma unroll
      for (int c = 0; c < 6; ++c) h7[c] = lx[c] + hvb[c];
      if (hB == 0){
        float* dst = h_all + ((size_t)(step + 1) * 1024 + t) * 6;
        #pragma unroll
        for (int c = 0; c < 6; ++c) dst[c] = h7[c];
      }
    }
    par ^= 1;
  }
}

extern "C" void kernel_launch(void* const* d_in, const int* in_sizes, int n_in,
                              void* d_out, int out_size, void* d_ws, size_t ws_size,
                              hipStream_t stream) {
  (void)in_sizes; (void)n_in; (void)out_size;

  const size_t avail = ws_size / 4;
  if (avail < 600000u) return;   // ~2.4 MB needed

  float* ws = (float*)d_ws;
  size_t off = 0;
  int*   flag   = (int*)(ws + off); off += 16;
  float* xs     = ws + off; off += 73728;
  float* wsW    = ws + off; off += 10800;
  float* Lx     = ws + off; off += 73728;
  float* WaG    = ws + off; off += 256;
  float* h_all  = ws + off; off += 79872;    // [13][1024][6]; [1..12] used
  float* y6part = ws + off; off += 294912;   // [12][4][1024][6]
  float* y6p2   = ws + off; off += 49152;    // [2][4][1024][6] parity buffers
  int*   bar    = (int*)(ws + off); off += 16;

  hipMemsetAsync(flag, 0, 4, stream);
  k_detect<<<288, 256, 0, stream>>>((const unsigned short*)d_in[0], 73728, flag);
  Ptr13 ptrs;
  for (int i = 0; i < 13; ++i) ptrs.p[i] = d_in[i];
  k_cvtAll<<<331, 256, 0, stream>>>(ptrs, xs, wsW, flag);
  k_prew<<<1, 256, 0, stream>>>(wsW, WaG, bar);

  float *Wx = wsW, *Wxo = wsW + 2048, *axo = wsW + 3584;
  float *Wh = wsW + 3600, *Who = wsW + 5648, *aho = wsW + 7184;
  float *Wy = wsW + 7200, *Wyo = wsW + 9248, *ayo = wsW + 10784;

  // Phase 1 (parallel over t,h): Lx[t] = pat_layer(x_t, Wx, ax, Wxo, axo)
  k_stageA<<<dim3(4, 12), 1024, 0, stream>>>(xs, WaG, Wx, Wxo, y6part);
  k_stageB<0><<<12, 1024, 0, stream>>>(y6part, axo, nullptr, Lx, nullptr, flag);

  // Phase 2: one persistent kernel, 4 blocks, 12 recurrence steps inside.
  k_phase2<<<4, 1024, 0, stream>>>(Lx, h_all, WaG + 64, Wh, Who, aho, y6p2, bar);

  // Phase 3 (parallel over t,h): y_t = x_t + pat_layer(h_t, Wy, ay, Wyo, ayo)
  k_stageA<<<dim3(4, 12), 1024, 0, stream>>>(h_all + 6144, WaG + 128, Wy, Wyo, y6part);
  k_stageB<2><<<12, 1024, 0, stream>>>(y6part, ayo, xs, nullptr, d_out, flag);
}

// Round 8
// 599.695 us; speedup vs baseline: 3.7274x; 3.7274x over previous
//
#include <hip/hip_runtime.h>
#include <hip/hip_bf16.h>

#define ALPHA 0.2f
// N=1024 particles, F_IN=6, NH=64, H=4 heads, T=12 steps.
// Identity: attend values are LINEAR in the 6-dim input row -> every head-attend
// runs in 6-dim space: out_h = (Sum_j w x_j) @ W_h; ELU(hv@W)@Wout is a per-row
// pointwise afterwards. Scores are linear too: s = x.(W@a_src), d = x.(W@a_dst).
// Dense per-row softmax (no binning -- round-7's binning was data-degenerate).

__device__ __forceinline__ float wredmax(float v){
  #pragma unroll
  for (int m = 1; m < 64; m <<= 1) v = fmaxf(v, __shfl_xor(v, m, 64));
  return v;
}

// ---------------- dtype detect + convert ----------------
__global__ void k_detect(const unsigned short* __restrict__ s, int n, int* __restrict__ flag){
  int i = blockIdx.x * 256 + threadIdx.x;
  if (i < n){
    unsigned short u = s[i];
    if ((u & 0x7F80u) == 0x7F80u) atomicOr(flag, 1);
  }
}

struct Ptr13 { const void* p[13]; };
__global__ void k_cvtAll(Ptr13 src, float* __restrict__ xs, float* __restrict__ wsW,
                         const int* __restrict__ flag){
  const int n = blockIdx.x * 256 + threadIdx.x;
  const int F = *flag;
  if (n < 73728){
    xs[n] = F ? ((const float*)src.p[0])[n]
              : __bfloat162float(((const __hip_bfloat16*)src.p[0])[n]);
    return;
  }
  const int m = n - 73728;
  if (m >= 10788) return;
  const int segend[12] = {1536,2048,3584,3596,5132,5644,7180,7192,8728,9240,10776,10788};
  const int dstoff[12] = {0,1536,2048,3584,3600,5136,5648,7184,7200,8736,9248,10784};
  int seg = 0;
  #pragma unroll
  for (int i = 0; i < 12; ++i) if (m >= segend[i]) seg = i + 1;
  const int local = m - (seg ? segend[seg - 1] : 0);
  float v;
  if (F) v = ((const float*)src.p[seg + 1])[local];
  else   v = __bfloat162float(((const __hip_bfloat16*)src.p[seg + 1])[local]);
  wsW[dstoff[seg] + local] = v;
}

// Wa[L][h][sd][8] = W @ a halves; zero h_cur (6144) + bar region (2048 ints).
__global__ void k_prew(const float* __restrict__ wsW, float* __restrict__ WaG,
                       float* __restrict__ h_cur, int* __restrict__ bar)
{
  const int gid = blockIdx.x * 256 + threadIdx.x;
  if (gid < 6144) h_cur[gid] = 0.f;
  else if (gid < 8192) bar[gid - 6144] = 0;
  if (blockIdx.x == 0 && threadIdx.x < 144){
    const int d = threadIdx.x;
    const int L = d / 48, r2 = d % 48, h = r2 / 12, sd = (r2 % 12) / 6, f = r2 % 6;
    const int Woff[3] = {0, 3600, 7200};     // Wx, Wh, Wy
    const int aoff[3] = {1536, 5136, 8736};  // ax, ah, ay
    float s = 0.f;
    for (int k = 0; k < 64; ++k)
      s += wsW[Woff[L] + h * 384 + f * 64 + k] * wsW[aoff[L] + h * 128 + sd * 64 + k];
    WaG[((L * 4 + h) * 2 + sd) * 8 + f] = s;
  }
}

// ---------------- dense 6-dim attend machinery ----------------
// vS layout: [1024][8] floats: 0..5 = feats, 6 = pad, 7 = dest score d.
__device__ __forceinline__ void stage_plain(const float* __restrict__ src,
                                            float* __restrict__ vS, const int t){
  const float4* s4 = (const float4*)src;
  for (int i = t; i < 1536; i += 256){
    const float4 v = s4[i];
    int g = i * 4;
    vS[(g / 6) * 8 + g % 6] = v.x; ++g;
    vS[(g / 6) * 8 + g % 6] = v.y; ++g;
    vS[(g / 6) * 8 + g % 6] = v.z; ++g;
    vS[(g / 6) * 8 + g % 6] = v.w;
  }
}
__device__ __forceinline__ void stage_sum4(const float* __restrict__ src, // [4][1024][6]
                                           float* __restrict__ vS, const int t){
  const float4* s4 = (const float4*)src;
  for (int i = t; i < 1536; i += 256){
    const float4 a = s4[i], b = s4[1536 + i], c = s4[3072 + i], d = s4[4608 + i];
    float4 v; v.x = a.x+b.x+c.x+d.x; v.y = a.y+b.y+c.y+d.y;
    v.z = a.z+b.z+c.z+d.z; v.w = a.w+b.w+c.w+d.w;
    int g = i * 4;
    vS[(g / 6) * 8 + g % 6] = v.x; ++g;
    vS[(g / 6) * 8 + g % 6] = v.y; ++g;
    vS[(g / 6) * 8 + g % 6] = v.z; ++g;
    vS[(g / 6) * 8 + g % 6] = v.w;
  }
}
// fills vS[.][7] = d, sS[r-r0] = s for own rows; returns block-max d.
// Callers must __syncthreads() between feats staging and this call.
__device__ __forceinline__ float stage_scores(float* __restrict__ vS,
    const float (&was)[6], const float (&wad)[6],
    float* __restrict__ sS, const int r0, const int R,
    float* __restrict__ red, const int t){
  float lmax = -1.0e30f;
  for (int r = t; r < 1024; r += 256){
    const float* row = &vS[r * 8];
    float d = 0.f, s = 0.f;
    #pragma unroll
    for (int c = 0; c < 6; ++c){ d += row[c] * wad[c]; s += row[c] * was[c]; }
    vS[r * 8 + 7] = d;
    lmax = fmaxf(lmax, d);
    if ((unsigned)(r - r0) < (unsigned)R) sS[r - r0] = s;
  }
  lmax = wredmax(lmax);
  if ((t & 63) == 0) red[t >> 6] = lmax;
  __syncthreads();
  return fmaxf(fmaxf(red[0], red[1]), fmaxf(red[2], red[3]));
}
// dense attend for one row, lanes split j JG ways; acc[6] = den.
__device__ __forceinline__ void attend_j(const float* __restrict__ vS,
    const float s, const float dmax, const int jg, const int JG, float acc[7]){
  float m = s + dmax; m = fmaxf(m, ALPHA * m);          // leaky(s+dmax) = row max
  float a0=0.f,a1=0.f,a2=0.f,a3=0.f,a4=0.f,a5=0.f,a6=0.f;
  for (int j = jg; j < 1024; j += JG){
    const float4 lo = *(const float4*)&vS[j * 8];
    const float4 hi = *(const float4*)&vS[j * 8 + 4];
    float e = s + hi.w; e = fmaxf(e, ALPHA * e);
    const float w = __expf(fminf(e - m, 0.f));
    a0 += w * lo.x; a1 += w * lo.y; a2 += w * lo.z; a3 += w * lo.w;
    a4 += w * hi.x; a5 += w * hi.y; a6 += w;
  }
  acc[0]=a0; acc[1]=a1; acc[2]=a2; acc[3]=a3; acc[4]=a4; acc[5]=a5; acc[6]=a6;
}

// ---------------- phases 1/3: head attends ----------------
// grid (4 heads, 12 t, 16 rowgroups of 64), 256 thr: 4 lanes/row.
__launch_bounds__(256)
__global__ void k_dA(const float* __restrict__ X, const float* __restrict__ WaL,
                     const float* __restrict__ W64, const float* __restrict__ Wout,
                     float* __restrict__ y6part)
{
  __shared__ float vS[1024 * 8];
  __shared__ float WS_[384], WoT_[384];
  __shared__ float sS[64], red[4];
  const int h = blockIdx.x, tb = blockIdx.y, r0 = blockIdx.z * 64;
  const int t = threadIdx.x;
  if (t < 384){
    WS_[t] = W64[h * 384 + t];
    const int f = t >> 6, k = t & 63;
    WoT_[f * 64 + k] = Wout[(h * 64 + k) * 6 + f];
  }
  float was[6], wad[6];
  #pragma unroll
  for (int c = 0; c < 6; ++c){ was[c] = WaL[h * 16 + c]; wad[c] = WaL[h * 16 + 8 + c]; }
  stage_plain(X + (size_t)tb * 6144, vS, t);
  __syncthreads();
  const float dmax = stage_scores(vS, was, wad, sS, r0, 64, red, t);
  const int r = t >> 2, jg = t & 3;
  float acc[7];
  attend_j(vS, sS[r], dmax, jg, 4, acc);
  #pragma unroll
  for (int m = 1; m < 4; m <<= 1)
    #pragma unroll
    for (int c = 0; c < 7; ++c) acc[c] += __shfl_xor(acc[c], m, 64);
  const float inv = 1.f / acc[6];                        // all 4 lanes hold sums
  float hvv[6];
  #pragma unroll
  for (int c = 0; c < 6; ++c) hvv[c] = acc[c] * inv;
  // pointwise: kq = jg, k = kq + 4*kk (broadcast LDS reads; conflict-free)
  float yp[6] = {0.f,0.f,0.f,0.f,0.f,0.f};
  for (int kk = 0; kk < 16; ++kk){
    const int k = jg + kk * 4;
    float o = 0.f;
    #pragma unroll
    for (int c = 0; c < 6; ++c) o += hvv[c] * WS_[c * 64 + k];
    o = o > 0.f ? o : (__expf(o) - 1.f);                 // ELU
    #pragma unroll
    for (int c = 0; c < 6; ++c) yp[c] += o * WoT_[c * 64 + k];
  }
  #pragma unroll
  for (int m = 1; m < 4; m <<= 1)
    #pragma unroll
    for (int c = 0; c < 6; ++c) yp[c] += __shfl_xor(yp[c], m, 64);
  if (jg == 0){
    float* dst = y6part + (((size_t)tb * 4 + h) * 1024 + r0 + r) * 6;
    #pragma unroll
    for (int c = 0; c < 6; ++c) dst[c] = yp[c];
  }
}

// phases 1/3: output attend. grid (16 rowgroups, 12 t), 256 thr, 4 lanes/row.
// MODE 0: f32out = hv (Lx). MODE 2: outv = addsrc + hv (final, dtype by flag).
template<int MODE>
__launch_bounds__(256)
__global__ void k_dB(const float* __restrict__ y6part, const float* __restrict__ ao,
                     const float* __restrict__ addsrc, float* __restrict__ f32out,
                     void* __restrict__ outv, const int* __restrict__ flag)
{
  __shared__ float vS[1024 * 8];
  __shared__ float sS[64], red[4];
  const int r0 = blockIdx.x * 64, tb = blockIdx.y;
  const int t = threadIdx.x;
  float was[6], wad[6];
  #pragma unroll
  for (int c = 0; c < 6; ++c){ was[c] = ao[c]; wad[c] = ao[6 + c]; }
  stage_sum4(y6part + (size_t)tb * 24576, vS, t);
  __syncthreads();
  const float dmax = stage_scores(vS, was, wad, sS, r0, 64, red, t);
  const int r = t >> 2, jg = t & 3;
  float acc[7];
  attend_j(vS, sS[r], dmax, jg, 4, acc);
  #pragma unroll
  for (int m = 1; m < 4; m <<= 1)
    #pragma unroll
    for (int c = 0; c < 7; ++c) acc[c] += __shfl_xor(acc[c], m, 64);
  if (jg == 0){
    const float inv = 1.f / acc[6];
    const int row = r0 + r;
    if (MODE == 0){
      float* dst = f32out + (size_t)tb * 6144 + row * 6;
      #pragma unroll
      for (int c = 0; c < 6; ++c) dst[c] = acc[c] * inv;
    } else {
      const float* a = addsrc + (size_t)tb * 6144 + row * 6;
      const int base = tb * 6144 + row * 6;
      if (*flag){
        float* dst = (float*)outv;
        #pragma unroll
        for (int c = 0; c < 6; ++c) dst[base + c] = a[c] + acc[c] * inv;
      } else {
        __hip_bfloat16* dst = (__hip_bfloat16*)outv;
        #pragma unroll
        for (int c = 0; c < 6; ++c) dst[base + c] = __float2bfloat16(a[c] + acc[c] * inv);
      }
    }
  }
}

// ---------------- phase 2: persistent 128-block kernel ----------------
// 2-level generation barrier: 16 leaf counters (8 arrivals each, 128B-spaced),
// 1 root, 16 per-leaf release generations. ~2-3 us vs cg's 36 us.
__device__ __forceinline__ void gbar(int* __restrict__ bar, const int bid, const int gen){
  __syncthreads();
  if (threadIdx.x == 0){
    __threadfence();
    const int lf = bid & 15;
    int v = atomicAdd(bar + lf * 32, 1);
    if (v == 7){
      int rr = atomicAdd(bar + 512, 1);
      if (rr == 15){
        atomicExch(bar + 512, 0);
        #pragma unroll
        for (int l = 0; l < 16; ++l) atomicExch(bar + l * 32, 0);
        __threadfence();
        #pragma unroll
        for (int l = 0; l < 16; ++l) atomicAdd(bar + 544 + l * 32, 1);
      }
    }
    while (atomicAdd(bar + 544 + lf * 32, 0) < gen) __builtin_amdgcn_s_sleep(1);
    __threadfence();
  }
  __syncthreads();
}

__launch_bounds__(256)
__global__ void k_p2(float* __restrict__ h_cur, const float* __restrict__ Lx,
                     float* __restrict__ h_all, const float* __restrict__ WaL,
                     const float* __restrict__ W64, const float* __restrict__ Wout,
                     const float* __restrict__ ao, float* __restrict__ y6p,
                     int* __restrict__ bar)
{
  __shared__ float vS[1024 * 8];
  __shared__ float WS_[384], WoT_[384];
  __shared__ float sS[32], red[4];
  const int bid = blockIdx.x, t = threadIdx.x;
  const int h = bid & 3, r0a = (bid >> 2) * 32;   // role A: head h, 32 rows
  const int r0b = bid * 8;                        // role B: 8 rows
  if (t < 384){
    WS_[t] = W64[h * 384 + t];
    const int f = t >> 6, k = t & 63;
    WoT_[f * 64 + k] = Wout[(h * 64 + k) * 6 + f];
  }
  float was[6], wad[6], aos[6], aod[6];
  #pragma unroll
  for (int c = 0; c < 6; ++c){
    was[c] = WaL[h * 16 + c]; wad[c] = WaL[h * 16 + 8 + c];
    aos[c] = ao[c];           aod[c] = ao[6 + c];
  }
  __syncthreads();

  for (int step = 0; step < 12; ++step){
    // ---- A: head attend + pointwise for (h, rows r0a..r0a+31) ----
    stage_plain(h_cur, vS, t);
    __syncthreads();
    {
      const float dmax = stage_scores(vS, was, wad, sS, r0a, 32, red, t);
      const int r = t >> 3, jg = t & 7;
      float acc[7];
      attend_j(vS, sS[r], dmax, jg, 8, acc);
      #pragma unroll
      for (int m = 1; m < 8; m <<= 1)
        #pragma unroll
        for (int c = 0; c < 7; ++c) acc[c] += __shfl_xor(acc[c], m, 64);
      const float inv = 1.f / acc[6];
      float hvv[6];
      #pragma unroll
      for (int c = 0; c < 6; ++c) hvv[c] = acc[c] * inv;
      float yp[6] = {0.f,0.f,0.f,0.f,0.f,0.f};
      for (int kk = 0; kk < 8; ++kk){
        const int k = jg + kk * 8;
        float o = 0.f;
        #pragma unroll
        for (int c = 0; c < 6; ++c) o += hvv[c] * WS_[c * 64 + k];
        o = o > 0.f ? o : (__expf(o) - 1.f);
        #pragma unroll
        for (int c = 0; c < 6; ++c) yp[c] += o * WoT_[c * 64 + k];
      }
      #pragma unroll
      for (int m = 1; m < 8; m <<= 1)
        #pragma unroll
        for (int c = 0; c < 6; ++c) yp[c] += __shfl_xor(yp[c], m, 64);
      if (jg == 0){
        float* dst = y6p + ((size_t)h * 1024 + r0a + r) * 6;
        #pragma unroll
        for (int c = 0; c < 6; ++c) dst[c] = yp[c];
      }
    }
    gbar(bar, bid, 2 * step + 1);
    // ---- B: output attend for rows r0b..r0b+7; h update ----
    stage_sum4(y6p, vS, t);
    __syncthreads();
    {
      const float dmax = stage_scores(vS, aos, aod, sS, r0b, 8, red, t);
      const int r = t >> 5, jg = t & 31;
      float acc[7];
      attend_j(vS, sS[r], dmax, jg, 32, acc);
      #pragma unroll
      for (int m = 1; m < 32; m <<= 1)
        #pragma unroll
        for (int c = 0; c < 7; ++c) acc[c] += __shfl_xor(acc[c], m, 64);
      if (jg == 0){
        const float inv = 1.f / acc[6];
        const int row = r0b + r;
        const float* lx = Lx + (size_t)step * 6144 + row * 6;
        float* hc = h_cur + row * 6;
        float* ha = h_all + (size_t)step * 6144 + row * 6;
        #pragma unroll
        for (int c = 0; c < 6; ++c){
          const float hvn = lx[c] + acc[c] * inv;
          hc[c] = hvn; ha[c] = hvn;
        }
      }
    }
    gbar(bar, bid, 2 * step + 2);
  }
}

extern "C" void kernel_launch(void* const* d_in, const int* in_sizes, int n_in,
                              void* d_out, int out_size, void* d_ws, size_t ws_size,
                              hipStream_t stream) {
  (void)in_sizes; (void)n_in; (void)out_size;

  const size_t avail = ws_size / 4;
  if (avail < 570000u) return;   // ~2.3 MB needed

  float* ws = (float*)d_ws;
  size_t off = 0;
  int*   flag   = (int*)(ws + off); off += 16;
  float* xs     = ws + off; off += 73728;
  float* wsW    = ws + off; off += 10800;
  float* Lx     = ws + off; off += 73728;
  float* WaG    = ws + off; off += 256;
  float* h_cur  = ws + off; off += 6144;
  float* h_all  = ws + off; off += 73728;    // [12][1024][6]; h after step t
  float* y6part = ws + off; off += 294912;   // [12][4][1024][6]
  float* y6p    = ws + off; off += 24576;    // [4][1024][6]
  int*   bar    = (int*)(ws + off); off += 2048;

  hipMemsetAsync(flag, 0, 4, stream);
  k_detect<<<288, 256, 0, stream>>>((const unsigned short*)d_in[0], 73728, flag);
  Ptr13 ptrs;
  for (int i = 0; i < 13; ++i) ptrs.p[i] = d_in[i];
  k_cvtAll<<<331, 256, 0, stream>>>(ptrs, xs, wsW, flag);
  k_prew<<<32, 256, 0, stream>>>(wsW, WaG, h_cur, bar);

  float *Wx = wsW, *Wxo = wsW + 2048, *axo = wsW + 3584;
  float *Wh = wsW + 3600, *Who = wsW + 5648, *aho = wsW + 7184;
  float *Wy = wsW + 7200, *Wyo = wsW + 9248, *ayo = wsW + 10784;

  // Phase 1: Lx[t] = pat_layer(x_t, Wx, ax, Wxo, axo)
  k_dA<<<dim3(4, 12, 16), 256, 0, stream>>>(xs, WaG, Wx, Wxo, y6part);
  k_dB<0><<<dim3(16, 12), 256, 0, stream>>>(y6part, axo, nullptr, Lx, nullptr, flag);

  // Phase 2: one persistent kernel, 128 blocks, 12 steps, tree-barrier synced.
  k_p2<<<128, 256, 0, stream>>>(h_cur, Lx, h_all, WaG + 64, Wh, Who, aho, y6p, bar);

  // Phase 3: y_t = x_t + pat_layer(h_t, Wy, ay, Wyo, ayo)
  k_dA<<<dim3(4, 12, 16), 256, 0, stream>>>(h_all, WaG + 128, Wy, Wyo, y6part);
  k_dB<2><<<dim3(16, 12), 256, 0, stream>>>(y6part, ayo, xs, nullptr, d_out, flag);
}